// Round 9
// baseline (9727.804 us; speedup 1.0000x reference)
//
#include <hip/hip_runtime.h>

#define Bsz 128
#define Tlen 1024
#define Din 256
#define Hdim 512

#define NBG 8    // batch groups (16 rows each)
#define NCG 16   // col groups per bg (32 h-cols each)

typedef __attribute__((ext_vector_type(8))) short short8;
typedef __attribute__((ext_vector_type(4))) float f32x4;
typedef __attribute__((ext_vector_type(4))) unsigned short ushort4_;
typedef __attribute__((ext_vector_type(4))) unsigned int uint4v;

// tagged h exchange: u32 = (bf16<<16) | tag ; layout [2 parity][NBG][16 rows][512 cols]
#define HBT_BYTES ((size_t)2 * NBG * 16 * Hdim * 4)  // 524,288
#define HT_OFF ((size_t)524288)

__device__ inline unsigned short f2bf(float f) {
    unsigned int u = __builtin_bit_cast(unsigned int, f);
    unsigned int lsb = (u >> 16) & 1u;
    u += 0x7fffu + lsb;  // RNE
    return (unsigned short)(u >> 16);
}
__device__ inline float bf2f(unsigned short u) {
    unsigned int v = ((unsigned int)u) << 16;
    return __builtin_bit_cast(float, v);
}
__device__ inline float sigm_f(float x) { return 1.f / (1.f + __expf(-x)); }
__device__ inline float tanh_f(float x) { return 1.f - 2.f / (__expf(2.f * x) + 1.f); }

// 512 compute threads: 2 chunks per thread
__device__ __forceinline__ void conv_x_to_lds(const float4* xv, int tid,
                                              unsigned char* xh, unsigned char* xl) {
#pragma unroll
    for (int i = 0; i < 2; i++) {
        int cidx = tid + i * 512;
        int row = cidx >> 6;
        int c4 = cidx & 63;
        float vv[4] = {xv[i].x, xv[i].y, xv[i].z, xv[i].w};
        ushort4_ vh, vl;
#pragma unroll
        for (int e = 0; e < 4; e++) {
            unsigned short hi = f2bf(vv[e]);
            vh[e] = hi;
            vl[e] = f2bf(vv[e] - bf2f(hi));
        }
        int a = ((row << 9) + (c4 << 3)) ^ ((row & 7) << 4);
        *(ushort4_*)(xh + a) = vh;
        *(ushort4_*)(xl + a) = vl;
    }
}

// chunk valid iff all 4 words carry tag == want (per-4B-word atomicity)
__device__ __forceinline__ bool chunk_ok(uint4v v, unsigned want) {
    unsigned m =
        ((v[0] ^ want) | (v[1] ^ want) | (v[2] ^ want) | (v[3] ^ want)) & 0xFFFFu;
    return m == 0;
}
// extract 4 bf16 (high halves) -> 8B into swizzled h_lds ; c in [0,2048)
__device__ __forceinline__ void chunk_to_lds(uint4v v, int c, unsigned char* h_lds) {
    int row = c >> 7;
    unsigned lo = (v[0] >> 16) | (v[1] & 0xFFFF0000u);
    unsigned hi = (v[2] >> 16) | (v[3] & 0xFFFF0000u);
    int a = ((row << 10) + ((c & 127) << 3)) ^ ((row & 7) << 4);
    *(unsigned long long*)(h_lds + a) =
        (unsigned long long)lo | ((unsigned long long)hi << 32);
}

__global__ __launch_bounds__(768, 1) void lstm_persist(
    const float* __restrict__ x, const float* __restrict__ Wih,
    const float* __restrict__ Whh, const float* __restrict__ bih,
    const float* __restrict__ bhh, unsigned int* __restrict__ hbt,
    float* __restrict__ hT) {
    __shared__ unsigned char h_lds[2 * 16 * 1024];  // dbuf [16][512] bf16, swizzled
    __shared__ unsigned char xh_lds[2 * 8192];      // dbuf [16][256] bf16 hi, swizzled
    __shared__ unsigned char xl_lds[2 * 8192];      // dbuf lo
    __shared__ float gates_w[8][16 * 17];           // per-wave [16 batch][16 gcol]

    const int tid = threadIdx.x;
    const int bid = blockIdx.x;
    const int bg = bid & 7;     // XCD-affine
    const int cg = bid >> 3;    // col group 0..15 (32 cols each)
    const int lane = tid & 63;
    const int w = tid >> 6;     // wave 0..11
    const bool comp = (w < 8);  // waves 0-7 compute, 8-11 exchange
    const int n15 = lane & 15;
    const int k8 = lane >> 4;
    const int grow = bg * 16;
    const int et = tid - 512;   // exchange thread id 0..255

    // compute-wave ownership: lane -> (batch myb, col mycol), 4 gates each
    const int gc = n15 & 3;
    const int gsel = n15 >> 2;
    const int myb = k8 * 4 + gsel;
    const int mycol = cg * 32 + (comp ? w : 0) * 4 + gc;

    short8 whh[16], wihh[8], wihl[8];
    float bias4[4];
    float4 xr[2];
    if (comp) {
        // ---- one-time: weight fragments. B-frag col n15 -> gate-row R ----
        const int R = (n15 >> 2) * Hdim + mycol;
        const float* wr = Whh + (size_t)R * Hdim;
#pragma unroll
        for (int kc = 0; kc < 16; kc++) {
            const float* p = wr + kc * 32 + k8 * 8;
            short8 f;
#pragma unroll
            for (int e = 0; e < 8; e++) f[e] = (short)f2bf(p[e]);
            whh[kc] = f;
        }
        const float* wr2 = Wih + (size_t)R * Din;
#pragma unroll
        for (int kc = 0; kc < 8; kc++) {
            const float* p = wr2 + kc * 32 + k8 * 8;
            short8 fh, fl;
#pragma unroll
            for (int e = 0; e < 8; e++) {
                float v = p[e];
                unsigned short hi = f2bf(v);
                fh[e] = (short)hi;
                fl[e] = (short)f2bf(v - bf2f(hi));
            }
            wihh[kc] = fh;
            wihl[kc] = fl;
        }
#pragma unroll
        for (int g = 0; g < 4; g++)
            bias4[g] = bih[g * Hdim + mycol] + bhh[g * Hdim + mycol];

        // ---- prologue: stage x[0] -> buf0; prefetch x[1] -> regs ----
        const float* xb = x + (size_t)grow * (Tlen * Din);
#pragma unroll
        for (int i = 0; i < 2; i++) {
            int cidx = tid + i * 512;
            int row = cidx >> 6;
            int c4 = cidx & 63;
            xr[i] = *(const float4*)(xb + (size_t)row * (Tlen * Din) + c4 * 4);
        }
        conv_x_to_lds(xr, tid, xh_lds, xl_lds);
#pragma unroll
        for (int i = 0; i < 2; i++) {
            int cidx = tid + i * 512;
            int row = cidx >> 6;
            int c4 = cidx & 63;
            xr[i] = *(const float4*)(xb + (size_t)row * (Tlen * Din) + Din + c4 * 4);
        }
    }
    __syncthreads();

    float c_reg = 0.f, h_last = 0.f;

    for (int t = 0; t < Tlen; ++t) {
        f32x4 acc0 = {0.f, 0.f, 0.f, 0.f}, acc1 = {0.f, 0.f, 0.f, 0.f};

        if (comp) {
            // conv xr (= x[t+1]) into buf[(t+1)&1]
            if (t + 1 < Tlen)
                conv_x_to_lds(xr, tid, xh_lds + ((t + 1) & 1) * 8192,
                              xl_lds + ((t + 1) & 1) * 8192);
            // x-side MFMAs on buf[t&1]
            unsigned char* xh = xh_lds + (t & 1) * 8192;
            unsigned char* xl = xl_lds + (t & 1) * 8192;
#pragma unroll
            for (int kc = 0; kc < 8; kc++) {
                int a = ((n15 << 9) + (kc << 6) + (k8 << 4)) ^ ((n15 & 7) << 4);
                short8 xhv = *(const short8*)(xh + a);
                short8 xlv = *(const short8*)(xl + a);
                acc0 = __builtin_amdgcn_mfma_f32_16x16x32_bf16(xhv, wihh[kc], acc0, 0, 0, 0);
                acc1 = __builtin_amdgcn_mfma_f32_16x16x32_bf16(xlv, wihh[kc], acc1, 0, 0, 0);
                if (kc & 1)
                    acc1 = __builtin_amdgcn_mfma_f32_16x16x32_bf16(xhv, wihl[kc], acc1, 0, 0, 0);
                else
                    acc0 = __builtin_amdgcn_mfma_f32_16x16x32_bf16(xhv, wihl[kc], acc0, 0, 0, 0);
            }
        } else {
            // ---- exchange waves: fill h_lds[buf t&1] with tag-t data ----
            unsigned char* hl = h_lds + (t & 1) * 16384;
            if (t == 0) {
#pragma unroll
                for (int i = 0; i < 8; i++) {
                    int c = et + i * 256;
                    int row = c >> 7;
                    int a = ((row << 10) + ((c & 127) << 3)) ^ ((row & 7) << 4);
                    *(unsigned long long*)(hl + a) = 0ULL;
                }
            } else {
                const unsigned want = (unsigned)t;
                const unsigned int* hb = hbt + ((size_t)(t & 1) * NBG + bg) * 8192;
                const unsigned int* pp0 = hb + (size_t)(et + 0 * 256) * 4;
                const unsigned int* pp1 = hb + (size_t)(et + 1 * 256) * 4;
                const unsigned int* pp2 = hb + (size_t)(et + 2 * 256) * 4;
                const unsigned int* pp3 = hb + (size_t)(et + 3 * 256) * 4;
                const unsigned int* pp4 = hb + (size_t)(et + 4 * 256) * 4;
                const unsigned int* pp5 = hb + (size_t)(et + 5 * 256) * 4;
                const unsigned int* pp6 = hb + (size_t)(et + 6 * 256) * 4;
                const unsigned int* pp7 = hb + (size_t)(et + 7 * 256) * 4;
                uint4v v0, v1, v2, v3, v4, v5, v6, v7;
                unsigned need = 0xFFu;
#define ISS(i, vi)                                                              \
    if (need & (1u << i))                                                       \
        asm volatile("global_load_dwordx4 %0, %1, off sc0 sc1"                  \
                     : "=&v"(vi) : "v"(pp##i) : "memory");
#define CHK(i, vi)                                                              \
    if ((need & (1u << i)) && chunk_ok(vi, want)) {                             \
        chunk_to_lds(vi, et + i * 256, hl);                                     \
        need &= ~(1u << i);                                                     \
    }
                ISS(0, v0) ISS(1, v1) ISS(2, v2) ISS(3, v3)
                ISS(4, v4) ISS(5, v5) ISS(6, v6) ISS(7, v7)
                asm volatile("s_waitcnt vmcnt(0)" ::: "memory");
                __builtin_amdgcn_sched_barrier(0);
                CHK(0, v0) CHK(1, v1) CHK(2, v2) CHK(3, v3)
                CHK(4, v4) CHK(5, v5) CHK(6, v6) CHK(7, v7)
                int rounds = 0;
                while (__ballot(need != 0) != 0ULL && ++rounds < (1 << 12)) {
                    unsigned before = need;
                    ISS(0, v0) ISS(1, v1) ISS(2, v2) ISS(3, v3)
                    ISS(4, v4) ISS(5, v5) ISS(6, v6) ISS(7, v7)
                    asm volatile("s_waitcnt vmcnt(0)" ::: "memory");
                    __builtin_amdgcn_sched_barrier(0);
                    CHK(0, v0) CHK(1, v1) CHK(2, v2) CHK(3, v3)
                    CHK(4, v4) CHK(5, v5) CHK(6, v6) CHK(7, v7)
                    if (__ballot(need != before) == 0ULL)
                        __builtin_amdgcn_s_sleep(1);
                }
#undef ISS
#undef CHK
            }
        }
        // barrier A: h_lds[t&1] ready (exchange ds_writes committed via lgkmcnt)
        asm volatile("s_waitcnt lgkmcnt(0)" ::: "memory");
        __builtin_amdgcn_s_barrier();
        __builtin_amdgcn_sched_barrier(0);

        if (comp) {
            // h-side MFMAs on h_lds[t&1]
            const unsigned char* hl = h_lds + (t & 1) * 16384;
#pragma unroll
            for (int kc = 0; kc < 16; kc++) {
                short8 a = *(const short8*)(hl + (((n15 << 10) + (kc << 6) + (k8 << 4)) ^
                                                 ((n15 & 7) << 4)));
                if (kc & 1)
                    acc1 = __builtin_amdgcn_mfma_f32_16x16x32_bf16(a, whh[kc], acc1, 0, 0, 0);
                else
                    acc0 = __builtin_amdgcn_mfma_f32_16x16x32_bf16(a, whh[kc], acc0, 0, 0, 0);
            }
            // prefetch x[t+2] -> regs (stays in flight across barrier C)
            if (t + 2 < Tlen) {
                const float* xb =
                    x + (size_t)grow * (Tlen * Din) + (size_t)(t + 2) * Din;
#pragma unroll
                for (int i = 0; i < 2; i++) {
                    int cidx = tid + i * 512;
                    int row = cidx >> 6;
                    int c4 = cidx & 63;
                    xr[i] = *(const float4*)(xb + (size_t)row * (Tlen * Din) + c4 * 4);
                }
            }
            // gates -> wave-private LDS; cell update; fire-and-forget publish
            float* gt = gates_w[w];
#pragma unroll
            for (int j2 = 0; j2 < 4; j2++)
                gt[(k8 * 4 + j2) * 17 + n15] = acc0[j2] + acc1[j2];
            float pre[4];
#pragma unroll
            for (int g = 0; g < 4; g++) pre[g] = gt[myb * 17 + g * 4 + gc] + bias4[g];
            float ig = sigm_f(pre[0]);
            float fg = sigm_f(pre[1]);
            float gg = tanh_f(pre[2]);
            float og = sigm_f(pre[3]);
            c_reg = fg * c_reg + ig * gg;
            h_last = og * tanh_f(c_reg);
            unsigned int word = ((unsigned int)f2bf(h_last) << 16) | (unsigned)(t + 1);
            unsigned int* dst = hbt + ((size_t)((t + 1) & 1) * NBG + bg) * 8192 +
                                (size_t)myb * Hdim + mycol;
            __hip_atomic_store(dst, word, __ATOMIC_RELAXED, __HIP_MEMORY_SCOPE_AGENT);
        }
        // barrier C: x dbuf WAR separation; no vmcnt drain (publish + prefetch in flight)
        asm volatile("s_waitcnt lgkmcnt(0)" ::: "memory");
        __builtin_amdgcn_s_barrier();
        __builtin_amdgcn_sched_barrier(0);
    }

    if (comp) hT[(size_t)(grow + myb) * Hdim + mycol] = h_last;
}

__global__ __launch_bounds__(256) void out_proj(const float* __restrict__ hT,
                                                const float* __restrict__ Wout,
                                                const float* __restrict__ bout,
                                                float* __restrict__ out) {
    __shared__ float h_s[16 * 512];
    __shared__ float w_s[64 * 69];
    const int tid = threadIdx.x;
    const int bt = blockIdx.x >> 2;
    const int ot = blockIdx.x & 3;
#pragma unroll
    for (int i = 0; i < 8; i++) {
        int cidx = tid + i * 256;
        int row = cidx >> 7;
        int c4 = cidx & 127;
        *(float4*)(&h_s[row * 512 + c4 * 4]) =
            *(const float4*)(hT + (size_t)(bt * 16 + row) * 512 + c4 * 4);
    }
    const int o = tid & 63;
    const int bq = tid >> 6;
    float acc[4] = {0.f, 0.f, 0.f, 0.f};
    for (int kc = 0; kc < 8; kc++) {
        __syncthreads();
#pragma unroll
        for (int i = 0; i < 4; i++) {
            int cidx = tid + i * 256;
            int row = cidx >> 4;
            int c4 = cidx & 15;
            float4 v = *(const float4*)(Wout + (size_t)(ot * 64 + row) * 512 + kc * 64 +
                                        c4 * 4);
            float* dst = &w_s[row * 69 + c4 * 4];
            dst[0] = v.x;
            dst[1] = v.y;
            dst[2] = v.z;
            dst[3] = v.w;
        }
        __syncthreads();
#pragma unroll 16
        for (int k = 0; k < 64; k++) {
            float wv = w_s[o * 69 + k];
#pragma unroll
            for (int bi = 0; bi < 4; bi++)
                acc[bi] += h_s[(bq * 4 + bi) * 512 + kc * 64 + k] * wv;
        }
    }
    float bo = bout[ot * 64 + o];
#pragma unroll
    for (int bi = 0; bi < 4; bi++)
        out[(size_t)(bt * 16 + bq * 4 + bi) * 256 + ot * 64 + o] = acc[bi] + bo;
}

extern "C" void kernel_launch(void* const* d_in, const int* in_sizes, int n_in,
                              void* d_out, int out_size, void* d_ws, size_t ws_size,
                              hipStream_t stream) {
    const float* x = (const float*)d_in[0];
    const float* Wih = (const float*)d_in[1];
    const float* Whh = (const float*)d_in[2];
    const float* bih = (const float*)d_in[3];
    const float* bhh = (const float*)d_in[4];
    const float* Wout = (const float*)d_in[5];
    const float* bout = (const float*)d_in[6];
    float* out = (float*)d_out;

    char* ws = (char*)d_ws;
    unsigned int* hbt = (unsigned int*)ws;
    float* hT = (float*)(ws + HT_OFF);

    hipMemsetAsync(hbt, 0, HBT_BYTES, stream);  // clear tags: replay determinism
    lstm_persist<<<dim3(NBG * NCG), dim3(768), 0, stream>>>(x, Wih, Whh, bih, bhh, hbt,
                                                            hT);
    out_proj<<<dim3(32), dim3(256), 0, stream>>>(hT, Wout, bout, out);
}

// Round 10
// 2181.905 us; speedup vs baseline: 4.4584x; 4.4584x over previous
//
#include <hip/hip_runtime.h>

#define Bsz 128
#define Tlen 1024
#define Din 256
#define Hdim 512

#define NBG 8    // batch groups (16 rows each)
#define NCG 16   // col groups per bg (32 h-cols each, 512-thread WGs)

typedef __attribute__((ext_vector_type(8))) short short8;
typedef __attribute__((ext_vector_type(4))) float f32x4;
typedef __attribute__((ext_vector_type(4))) unsigned short ushort4_;
typedef __attribute__((ext_vector_type(4))) unsigned int uint4v;

// tagged h exchange: u32 = (bf16<<16) | tag ; layout [2 parity][NBG][16 rows][512 cols]
#define HBT_BYTES ((size_t)2 * NBG * 16 * Hdim * 4)  // 524,288
#define HT_OFF ((size_t)524288)
#define XP_OFF ((size_t)786432)                       // hbt 512K + hT 256K
#define XP_BYTES ((size_t)1 << 30)                    // fp32 xp[1024][128][512] float4

__device__ inline unsigned short f2bf(float f) {
    unsigned int u = __builtin_bit_cast(unsigned int, f);
    unsigned int lsb = (u >> 16) & 1u;
    u += 0x7fffu + lsb;  // RNE
    return (unsigned short)(u >> 16);
}
__device__ inline float bf2f(unsigned short u) {
    unsigned int v = ((unsigned int)u) << 16;
    return __builtin_bit_cast(float, v);
}
__device__ inline float sigm_f(float x) { return 1.f / (1.f + __expf(-x)); }
__device__ inline float tanh_f(float x) { return 1.f - 2.f / (__expf(2.f * x) + 1.f); }

// 512 threads: 2 chunks per thread
__device__ __forceinline__ void conv_x_to_lds(const float4* xv, int tid,
                                              unsigned char* xh, unsigned char* xl) {
#pragma unroll
    for (int i = 0; i < 2; i++) {
        int cidx = tid + i * 512;
        int row = cidx >> 6;
        int c4 = cidx & 63;
        float vv[4] = {xv[i].x, xv[i].y, xv[i].z, xv[i].w};
        ushort4_ vh, vl;
#pragma unroll
        for (int e = 0; e < 4; e++) {
            unsigned short hi = f2bf(vv[e]);
            vh[e] = hi;
            vl[e] = f2bf(vv[e] - bf2f(hi));
        }
        int a = ((row << 9) + (c4 << 3)) ^ ((row & 7) << 4);
        *(ushort4_*)(xh + a) = vh;
        *(ushort4_*)(xl + a) = vl;
    }
}

__device__ __forceinline__ bool chunk_ok(uint4v v, unsigned want) {
    unsigned m =
        ((v[0] ^ want) | (v[1] ^ want) | (v[2] ^ want) | (v[3] ^ want)) & 0xFFFFu;
    return m == 0;
}
__device__ __forceinline__ void chunk_to_lds(uint4v v, int c, unsigned char* h_lds) {
    int row = c >> 7;
    unsigned lo = (v[0] >> 16) | (v[1] & 0xFFFF0000u);
    unsigned hi = (v[2] >> 16) | (v[3] & 0xFFFF0000u);
    int a = ((row << 10) + ((c & 127) << 3)) ^ ((row & 7) << 4);
    *(unsigned long long*)(h_lds + a) =
        (unsigned long long)lo | ((unsigned long long)hi << 32);
}

// ================= PHASE 1: xp = x . W_ih^T (hi/lo split), acc-layout output ========
__global__ __launch_bounds__(512, 1) void xproj_kernel(const float* __restrict__ x,
                                                       const float* __restrict__ Wih,
                                                       float4* __restrict__ xp) {
    __shared__ unsigned char xh_lds[2 * 8192];
    __shared__ unsigned char xl_lds[2 * 8192];
    const int tid = threadIdx.x;
    const int bid = blockIdx.x;
    const int bg = bid & 7;
    const int cg = (bid >> 3) & 15;
    const int half = bid >> 7;  // 0/1: t-range split
    const int lane = tid & 63;
    const int w = tid >> 6;
    const int n15 = lane & 15;
    const int k8 = lane >> 4;
    const int grow = bg * 16;
    const int gc = n15 & 3;
    const int mycol = cg * 32 + w * 4 + gc;
    const int R = (n15 >> 2) * Hdim + mycol;

    short8 wihh[8], wihl[8];
    {
        const float* wr2 = Wih + (size_t)R * Din;
#pragma unroll
        for (int kc = 0; kc < 8; kc++) {
            const float* p = wr2 + kc * 32 + k8 * 8;
            short8 fh, fl;
#pragma unroll
            for (int e = 0; e < 8; e++) {
                float v = p[e];
                unsigned short hi = f2bf(v);
                fh[e] = (short)hi;
                fl[e] = (short)f2bf(v - bf2f(hi));
            }
            wihh[kc] = fh;
            wihl[kc] = fl;
        }
    }
    const int t0 = half * 512, t1 = t0 + 512;
    float4 xr[2];
    {
        const float* xb = x + (size_t)grow * (Tlen * Din) + (size_t)t0 * Din;
#pragma unroll
        for (int i = 0; i < 2; i++) {
            int cidx = tid + i * 512;
            int row = cidx >> 6;
            int c4 = cidx & 63;
            xr[i] = *(const float4*)(xb + (size_t)row * (Tlen * Din) + c4 * 4);
        }
    }
    for (int t = t0; t < t1; ++t) {
        conv_x_to_lds(xr, tid, xh_lds + (t & 1) * 8192, xl_lds + (t & 1) * 8192);
        if (t + 1 < t1) {
            const float* xb = x + (size_t)grow * (Tlen * Din) + (size_t)(t + 1) * Din;
#pragma unroll
            for (int i = 0; i < 2; i++) {
                int cidx = tid + i * 512;
                int row = cidx >> 6;
                int c4 = cidx & 63;
                xr[i] = *(const float4*)(xb + (size_t)row * (Tlen * Din) + c4 * 4);
            }
        }
        asm volatile("s_waitcnt lgkmcnt(0)" ::: "memory");
        __builtin_amdgcn_s_barrier();
        __builtin_amdgcn_sched_barrier(0);
        unsigned char* xh = xh_lds + (t & 1) * 8192;
        unsigned char* xl = xl_lds + (t & 1) * 8192;
        f32x4 acc0 = {0.f, 0.f, 0.f, 0.f}, acc1 = {0.f, 0.f, 0.f, 0.f};
#pragma unroll
        for (int kc = 0; kc < 8; kc++) {
            int a = ((n15 << 9) + (kc << 6) + (k8 << 4)) ^ ((n15 & 7) << 4);
            short8 xhv = *(const short8*)(xh + a);
            short8 xlv = *(const short8*)(xl + a);
            acc0 = __builtin_amdgcn_mfma_f32_16x16x32_bf16(xhv, wihh[kc], acc0, 0, 0, 0);
            acc1 = __builtin_amdgcn_mfma_f32_16x16x32_bf16(xlv, wihh[kc], acc1, 0, 0, 0);
            if (kc & 1)
                acc1 = __builtin_amdgcn_mfma_f32_16x16x32_bf16(xhv, wihl[kc], acc1, 0, 0, 0);
            else
                acc0 = __builtin_amdgcn_mfma_f32_16x16x32_bf16(xhv, wihl[kc], acc0, 0, 0, 0);
        }
        float4 o;
        o.x = acc0[0] + acc1[0];
        o.y = acc0[1] + acc1[1];
        o.z = acc0[2] + acc1[2];
        o.w = acc0[3] + acc1[3];
        xp[((size_t)t * 128 + (bg * 16 + cg)) * 512 + tid] = o;
    }
}

// ================= PHASE 2: recurrence only (h-MFMA seeded from xp) =================
__global__ __launch_bounds__(512, 1) void lstm_persist_xp(
    const float4* __restrict__ xp, const float* __restrict__ Whh,
    const float* __restrict__ bih, const float* __restrict__ bhh,
    unsigned int* __restrict__ hbt, float* __restrict__ hT) {
    __shared__ unsigned char h_lds[16 * 1024];
    __shared__ float gates_w[8][16 * 17];
    const int tid = threadIdx.x;
    const int bid = blockIdx.x;
    const int bg = bid & 7;
    const int cg = bid >> 3;
    const int lane = tid & 63;
    const int w = tid >> 6;
    const int n15 = lane & 15;
    const int k8 = lane >> 4;
    const int grow = bg * 16;
    const int gc = n15 & 3;
    const int gsel = n15 >> 2;
    const int myb = k8 * 4 + gsel;
    const int mycol = cg * 32 + w * 4 + gc;
    const int R = (n15 >> 2) * Hdim + mycol;

    short8 whh[16];
    {
        const float* wr = Whh + (size_t)R * Hdim;
#pragma unroll
        for (int kc = 0; kc < 16; kc++) {
            const float* p = wr + kc * 32 + k8 * 8;
            short8 f;
#pragma unroll
            for (int e = 0; e < 8; e++) f[e] = (short)f2bf(p[e]);
            whh[kc] = f;
        }
    }
    float bias4[4];
#pragma unroll
    for (int g = 0; g < 4; g++) bias4[g] = bih[g * Hdim + mycol] + bhh[g * Hdim + mycol];

    const size_t xpbase = (size_t)(bg * 16 + cg) * 512 + tid;
    float4 xpc = xp[xpbase];  // t = 0
    float c_reg = 0.f, h_last = 0.f;

    for (int t = 0; t < Tlen; ++t) {
        // --- sweep + validate h(t) ---
        const unsigned int* hb = hbt + ((size_t)(t & 1) * NBG + bg) * 8192;
        const unsigned int* p0 = hb + (size_t)tid * 4;
        const unsigned int* p1 = hb + (size_t)(tid + 512) * 4;
        const unsigned int* p2 = hb + (size_t)(tid + 1024) * 4;
        const unsigned int* p3 = hb + (size_t)(tid + 1536) * 4;
        if (t > 0) {
            uint4v r0, r1, r2, r3;
            asm volatile(
                "global_load_dwordx4 %0, %4, off sc0 sc1\n\t"
                "global_load_dwordx4 %1, %5, off sc0 sc1\n\t"
                "global_load_dwordx4 %2, %6, off sc0 sc1\n\t"
                "global_load_dwordx4 %3, %7, off sc0 sc1"
                : "=&v"(r0), "=&v"(r1), "=&v"(r2), "=&v"(r3)
                : "v"(p0), "v"(p1), "v"(p2), "v"(p3)
                : "memory");
            const unsigned want = (unsigned)t;
            asm volatile("s_waitcnt vmcnt(0)" ::: "memory");
            __builtin_amdgcn_sched_barrier(0);
            unsigned need = 0;
            if (chunk_ok(r0, want)) chunk_to_lds(r0, tid, h_lds); else need |= 1u;
            if (chunk_ok(r1, want)) chunk_to_lds(r1, tid + 512, h_lds); else need |= 2u;
            if (chunk_ok(r2, want)) chunk_to_lds(r2, tid + 1024, h_lds); else need |= 4u;
            if (chunk_ok(r3, want)) chunk_to_lds(r3, tid + 1536, h_lds); else need |= 8u;
            int rounds = 0;
            while (need && ++rounds < (1 << 14)) {
                if (rounds > 6) __builtin_amdgcn_s_sleep(2);
                if (need & 1u)
                    asm volatile("global_load_dwordx4 %0, %1, off sc0 sc1"
                                 : "=&v"(r0) : "v"(p0) : "memory");
                if (need & 2u)
                    asm volatile("global_load_dwordx4 %0, %1, off sc0 sc1"
                                 : "=&v"(r1) : "v"(p1) : "memory");
                if (need & 4u)
                    asm volatile("global_load_dwordx4 %0, %1, off sc0 sc1"
                                 : "=&v"(r2) : "v"(p2) : "memory");
                if (need & 8u)
                    asm volatile("global_load_dwordx4 %0, %1, off sc0 sc1"
                                 : "=&v"(r3) : "v"(p3) : "memory");
                asm volatile("s_waitcnt vmcnt(0)" ::: "memory");
                __builtin_amdgcn_sched_barrier(0);
                if ((need & 1u) && chunk_ok(r0, want)) { chunk_to_lds(r0, tid, h_lds); need &= ~1u; }
                if ((need & 2u) && chunk_ok(r1, want)) { chunk_to_lds(r1, tid + 512, h_lds); need &= ~2u; }
                if ((need & 4u) && chunk_ok(r2, want)) { chunk_to_lds(r2, tid + 1024, h_lds); need &= ~4u; }
                if ((need & 8u) && chunk_ok(r3, want)) { chunk_to_lds(r3, tid + 1536, h_lds); need &= ~8u; }
            }
        } else {
#pragma unroll
            for (int i = 0; i < 4; i++) {
                int c = tid + i * 512;
                int row = c >> 7;
                int a = ((row << 10) + ((c & 127) << 3)) ^ ((row & 7) << 4);
                *(unsigned long long*)(h_lds + a) = 0ULL;
            }
        }
        // prefetch xp(t+1): in flight across barrier A + h-MFMA + cell
        float4 xpn = xpc;
        if (t + 1 < Tlen) xpn = xp[(size_t)(t + 1) * (128 * 512) + xpbase];
        // barrier A (LDS hazards only; xp load stays in flight)
        asm volatile("s_waitcnt lgkmcnt(0)" ::: "memory");
        __builtin_amdgcn_s_barrier();
        __builtin_amdgcn_sched_barrier(0);

        // h-MFMAs, acc seeded with xp(t)
        f32x4 acc0 = {xpc.x, xpc.y, xpc.z, xpc.w};
        f32x4 acc1 = {0.f, 0.f, 0.f, 0.f};
#pragma unroll
        for (int kc = 0; kc < 16; kc++) {
            short8 a = *(const short8*)(h_lds + (((n15 << 10) + (kc << 6) + (k8 << 4)) ^
                                                ((n15 & 7) << 4)));
            if (kc & 1)
                acc1 = __builtin_amdgcn_mfma_f32_16x16x32_bf16(a, whh[kc], acc1, 0, 0, 0);
            else
                acc0 = __builtin_amdgcn_mfma_f32_16x16x32_bf16(a, whh[kc], acc0, 0, 0, 0);
        }
        // gates -> wave-private LDS; cell; fire-and-forget tagged publish
        float* gt = gates_w[w];
#pragma unroll
        for (int j2 = 0; j2 < 4; j2++) gt[(k8 * 4 + j2) * 17 + n15] = acc0[j2] + acc1[j2];
        {
            float pre[4];
#pragma unroll
            for (int g = 0; g < 4; g++) pre[g] = gt[myb * 17 + g * 4 + gc] + bias4[g];
            float ig = sigm_f(pre[0]);
            float fg = sigm_f(pre[1]);
            float gg = tanh_f(pre[2]);
            float og = sigm_f(pre[3]);
            c_reg = fg * c_reg + ig * gg;
            h_last = og * tanh_f(c_reg);
            unsigned int word = ((unsigned int)f2bf(h_last) << 16) | (unsigned)(t + 1);
            unsigned int* dst = hbt + ((size_t)((t + 1) & 1) * NBG + bg) * 8192 +
                                (size_t)myb * Hdim + mycol;
            __hip_atomic_store(dst, word, __ATOMIC_RELAXED, __HIP_MEMORY_SCOPE_AGENT);
        }
        xpc = xpn;
        // barrier C (no vmcnt drain: publish store in flight)
        asm volatile("s_waitcnt lgkmcnt(0)" ::: "memory");
        __builtin_amdgcn_s_barrier();
        __builtin_amdgcn_sched_barrier(0);
    }
    hT[(size_t)(grow + myb) * Hdim + mycol] = h_last;
}

// ================= FALLBACK: exact R7 fused kernel ==================================
__global__ __launch_bounds__(512, 1) void lstm_persist_fused(
    const float* __restrict__ x, const float* __restrict__ Wih,
    const float* __restrict__ Whh, const float* __restrict__ bih,
    const float* __restrict__ bhh, unsigned int* __restrict__ hbt,
    float* __restrict__ hT) {
    __shared__ unsigned char h_lds[16 * 1024];
    __shared__ unsigned char xh_lds[2 * 8192];
    __shared__ unsigned char xl_lds[2 * 8192];
    __shared__ float gates_w[8][16 * 17];

    const int tid = threadIdx.x;
    const int bid = blockIdx.x;
    const int bg = bid & 7;
    const int cg = bid >> 3;
    const int lane = tid & 63;
    const int w = tid >> 6;
    const int n15 = lane & 15;
    const int k8 = lane >> 4;
    const int grow = bg * 16;
    const int gc = n15 & 3;
    const int gsel = n15 >> 2;
    const int myb = k8 * 4 + gsel;
    const int mycol = cg * 32 + w * 4 + gc;

    const int R = (n15 >> 2) * Hdim + mycol;
    short8 whh[16], wihh[8], wihl[8];
    {
        const float* wr = Whh + (size_t)R * Hdim;
#pragma unroll
        for (int kc = 0; kc < 16; kc++) {
            const float* p = wr + kc * 32 + k8 * 8;
            short8 f;
#pragma unroll
            for (int e = 0; e < 8; e++) f[e] = (short)f2bf(p[e]);
            whh[kc] = f;
        }
        const float* wr2 = Wih + (size_t)R * Din;
#pragma unroll
        for (int kc = 0; kc < 8; kc++) {
            const float* p = wr2 + kc * 32 + k8 * 8;
            short8 fh, fl;
#pragma unroll
            for (int e = 0; e < 8; e++) {
                float v = p[e];
                unsigned short hi = f2bf(v);
                fh[e] = (short)hi;
                fl[e] = (short)f2bf(v - bf2f(hi));
            }
            wihh[kc] = fh;
            wihl[kc] = fl;
        }
    }
    float bias4[4];
#pragma unroll
    for (int g = 0; g < 4; g++) bias4[g] = bih[g * Hdim + mycol] + bhh[g * Hdim + mycol];

    float4 xr[2];
    {
        const float* xb = x + (size_t)grow * (Tlen * Din);
#pragma unroll
        for (int i = 0; i < 2; i++) {
            int cidx = tid + i * 512;
            int row = cidx >> 6;
            int c4 = cidx & 63;
            xr[i] = *(const float4*)(xb + (size_t)row * (Tlen * Din) + c4 * 4);
        }
        conv_x_to_lds(xr, tid, xh_lds, xl_lds);
#pragma unroll
        for (int i = 0; i < 2; i++) {
            int cidx = tid + i * 512;
            int row = cidx >> 6;
            int c4 = cidx & 63;
            xr[i] = *(const float4*)(xb + (size_t)row * (Tlen * Din) + Din + c4 * 4);
        }
    }
    __syncthreads();

    float c_reg = 0.f, h_last = 0.f;

    for (int t = 0; t < Tlen; ++t) {
        if (t + 1 < Tlen)
            conv_x_to_lds(xr, tid, xh_lds + ((t + 1) & 1) * 8192,
                          xl_lds + ((t + 1) & 1) * 8192);
        const unsigned int* hb = hbt + ((size_t)(t & 1) * NBG + bg) * 8192;
        const unsigned int* p0 = hb + (size_t)tid * 4;
        const unsigned int* p1 = hb + (size_t)(tid + 512) * 4;
        const unsigned int* p2 = hb + (size_t)(tid + 1024) * 4;
        const unsigned int* p3 = hb + (size_t)(tid + 1536) * 4;
        uint4v r0, r1, r2, r3;
        if (t > 0) {
            asm volatile(
                "global_load_dwordx4 %0, %4, off sc0 sc1\n\t"
                "global_load_dwordx4 %1, %5, off sc0 sc1\n\t"
                "global_load_dwordx4 %2, %6, off sc0 sc1\n\t"
                "global_load_dwordx4 %3, %7, off sc0 sc1"
                : "=&v"(r0), "=&v"(r1), "=&v"(r2), "=&v"(r3)
                : "v"(p0), "v"(p1), "v"(p2), "v"(p3)
                : "memory");
        }
        unsigned char* xh = xh_lds + (t & 1) * 8192;
        unsigned char* xl = xl_lds + (t & 1) * 8192;
        f32x4 acc0 = {0.f, 0.f, 0.f, 0.f}, acc1 = {0.f, 0.f, 0.f, 0.f};
#pragma unroll
        for (int kc = 0; kc < 8; kc++) {
            int a = ((n15 << 9) + (kc << 6) + (k8 << 4)) ^ ((n15 & 7) << 4);
            short8 xhv = *(const short8*)(xh + a);
            short8 xlv = *(const short8*)(xl + a);
            acc0 = __builtin_amdgcn_mfma_f32_16x16x32_bf16(xhv, wihh[kc], acc0, 0, 0, 0);
            acc1 = __builtin_amdgcn_mfma_f32_16x16x32_bf16(xlv, wihh[kc], acc1, 0, 0, 0);
            if (kc & 1)
                acc1 = __builtin_amdgcn_mfma_f32_16x16x32_bf16(xhv, wihl[kc], acc1, 0, 0, 0);
            else
                acc0 = __builtin_amdgcn_mfma_f32_16x16x32_bf16(xhv, wihl[kc], acc0, 0, 0, 0);
        }
        if (t > 0) {
            const unsigned want = (unsigned)t;
            asm volatile("s_waitcnt vmcnt(0)" ::: "memory");
            __builtin_amdgcn_sched_barrier(0);
            unsigned need = 0;
            if (chunk_ok(r0, want)) chunk_to_lds(r0, tid, h_lds); else need |= 1u;
            if (chunk_ok(r1, want)) chunk_to_lds(r1, tid + 512, h_lds); else need |= 2u;
            if (chunk_ok(r2, want)) chunk_to_lds(r2, tid + 1024, h_lds); else need |= 4u;
            if (chunk_ok(r3, want)) chunk_to_lds(r3, tid + 1536, h_lds); else need |= 8u;
            int rounds = 0;
            while (need && ++rounds < (1 << 14)) {
                if (rounds > 6) __builtin_amdgcn_s_sleep(2);
                if (need & 1u)
                    asm volatile("global_load_dwordx4 %0, %1, off sc0 sc1"
                                 : "=&v"(r0) : "v"(p0) : "memory");
                if (need & 2u)
                    asm volatile("global_load_dwordx4 %0, %1, off sc0 sc1"
                                 : "=&v"(r1) : "v"(p1) : "memory");
                if (need & 4u)
                    asm volatile("global_load_dwordx4 %0, %1, off sc0 sc1"
                                 : "=&v"(r2) : "v"(p2) : "memory");
                if (need & 8u)
                    asm volatile("global_load_dwordx4 %0, %1, off sc0 sc1"
                                 : "=&v"(r3) : "v"(p3) : "memory");
                asm volatile("s_waitcnt vmcnt(0)" ::: "memory");
                __builtin_amdgcn_sched_barrier(0);
                if ((need & 1u) && chunk_ok(r0, want)) { chunk_to_lds(r0, tid, h_lds); need &= ~1u; }
                if ((need & 2u) && chunk_ok(r1, want)) { chunk_to_lds(r1, tid + 512, h_lds); need &= ~2u; }
                if ((need & 4u) && chunk_ok(r2, want)) { chunk_to_lds(r2, tid + 1024, h_lds); need &= ~4u; }
                if ((need & 8u) && chunk_ok(r3, want)) { chunk_to_lds(r3, tid + 1536, h_lds); need &= ~8u; }
            }
        } else {
#pragma unroll
            for (int i = 0; i < 4; i++) {
                int c = tid + i * 512;
                int row = c >> 7;
                int a = ((row << 10) + ((c & 127) << 3)) ^ ((row & 7) << 4);
                *(unsigned long long*)(h_lds + a) = 0ULL;
            }
        }
        __syncthreads();
#pragma unroll
        for (int kc = 0; kc < 16; kc++) {
            short8 a = *(const short8*)(h_lds + (((n15 << 10) + (kc << 6) + (k8 << 4)) ^
                                                ((n15 & 7) << 4)));
            if (kc & 1)
                acc1 = __builtin_amdgcn_mfma_f32_16x16x32_bf16(a, whh[kc], acc1, 0, 0, 0);
            else
                acc0 = __builtin_amdgcn_mfma_f32_16x16x32_bf16(a, whh[kc], acc0, 0, 0, 0);
        }
        if (t + 2 < Tlen) {
            const float* xb = x + (size_t)grow * (Tlen * Din) + (size_t)(t + 2) * Din;
#pragma unroll
            for (int i = 0; i < 2; i++) {
                int cidx = tid + i * 512;
                int row = cidx >> 6;
                int c4 = cidx & 63;
                xr[i] = *(const float4*)(xb + (size_t)row * (Tlen * Din) + c4 * 4);
            }
        }
        float* gt = gates_w[w];
#pragma unroll
        for (int j2 = 0; j2 < 4; j2++) gt[(k8 * 4 + j2) * 17 + n15] = acc0[j2] + acc1[j2];
        {
            float pre[4];
#pragma unroll
            for (int g = 0; g < 4; g++) pre[g] = gt[myb * 17 + g * 4 + gc] + bias4[g];
            float ig = sigm_f(pre[0]);
            float fg = sigm_f(pre[1]);
            float gg = tanh_f(pre[2]);
            float og = sigm_f(pre[3]);
            c_reg = fg * c_reg + ig * gg;
            h_last = og * tanh_f(c_reg);
            unsigned int word = ((unsigned int)f2bf(h_last) << 16) | (unsigned)(t + 1);
            unsigned int* dst = hbt + ((size_t)((t + 1) & 1) * NBG + bg) * 8192 +
                                (size_t)myb * Hdim + mycol;
            __hip_atomic_store(dst, word, __ATOMIC_RELAXED, __HIP_MEMORY_SCOPE_AGENT);
        }
        __syncthreads();
    }
    hT[(size_t)(grow + myb) * Hdim + mycol] = h_last;
}

__global__ __launch_bounds__(256) void out_proj(const float* __restrict__ hT,
                                                const float* __restrict__ Wout,
                                                const float* __restrict__ bout,
                                                float* __restrict__ out) {
    __shared__ float h_s[16 * 512];
    __shared__ float w_s[64 * 69];
    const int tid = threadIdx.x;
    const int bt = blockIdx.x >> 2;
    const int ot = blockIdx.x & 3;
#pragma unroll
    for (int i = 0; i < 8; i++) {
        int cidx = tid + i * 256;
        int row = cidx >> 7;
        int c4 = cidx & 127;
        *(float4*)(&h_s[row * 512 + c4 * 4]) =
            *(const float4*)(hT + (size_t)(bt * 16 + row) * 512 + c4 * 4);
    }
    const int o = tid & 63;
    const int bq = tid >> 6;
    float acc[4] = {0.f, 0.f, 0.f, 0.f};
    for (int kc = 0; kc < 8; kc++) {
        __syncthreads();
#pragma unroll
        for (int i = 0; i < 4; i++) {
            int cidx = tid + i * 256;
            int row = cidx >> 4;
            int c4 = cidx & 15;
            float4 v = *(const float4*)(Wout + (size_t)(ot * 64 + row) * 512 + kc * 64 +
                                        c4 * 4);
            float* dst = &w_s[row * 69 + c4 * 4];
            dst[0] = v.x;
            dst[1] = v.y;
            dst[2] = v.z;
            dst[3] = v.w;
        }
        __syncthreads();
#pragma unroll 16
        for (int k = 0; k < 64; k++) {
            float wv = w_s[o * 69 + k];
#pragma unroll
            for (int bi = 0; bi < 4; bi++)
                acc[bi] += h_s[(bq * 4 + bi) * 512 + kc * 64 + k] * wv;
        }
    }
    float bo = bout[ot * 64 + o];
#pragma unroll
    for (int bi = 0; bi < 4; bi++)
        out[(size_t)(bt * 16 + bq * 4 + bi) * 256 + ot * 64 + o] = acc[bi] + bo;
}

extern "C" void kernel_launch(void* const* d_in, const int* in_sizes, int n_in,
                              void* d_out, int out_size, void* d_ws, size_t ws_size,
                              hipStream_t stream) {
    const float* x = (const float*)d_in[0];
    const float* Wih = (const float*)d_in[1];
    const float* Whh = (const float*)d_in[2];
    const float* bih = (const float*)d_in[3];
    const float* bhh = (const float*)d_in[4];
    const float* Wout = (const float*)d_in[5];
    const float* bout = (const float*)d_in[6];
    float* out = (float*)d_out;

    char* ws = (char*)d_ws;
    unsigned int* hbt = (unsigned int*)ws;
    float* hT = (float*)(ws + HT_OFF);
    float4* xp = (float4*)(ws + XP_OFF);

    hipMemsetAsync(hbt, 0, HBT_BYTES, stream);  // clear tags: replay determinism
    if (ws_size >= XP_OFF + XP_BYTES) {
        xproj_kernel<<<dim3(256), dim3(512), 0, stream>>>(x, Wih, xp);
        lstm_persist_xp<<<dim3(NBG * NCG), dim3(512), 0, stream>>>(xp, Whh, bih, bhh,
                                                                   hbt, hT);
    } else {
        lstm_persist_fused<<<dim3(NBG * NCG), dim3(512), 0, stream>>>(x, Wih, Whh, bih,
                                                                      bhh, hbt, hT);
    }
    out_proj<<<dim3(32), dim3(256), 0, stream>>>(hT, Wout, bout, out);
}

// Round 11
// 2009.479 us; speedup vs baseline: 4.8410x; 1.0858x over previous
//
#include <hip/hip_runtime.h>

#define Bsz 128
#define Tlen 1024
#define Din 256
#define Hdim 512

#define NBG 8    // batch groups (16 rows each)
#define NCG 16   // col groups per bg (32 h-cols each, 512-thread WGs)

typedef __attribute__((ext_vector_type(8))) short short8;
typedef __attribute__((ext_vector_type(4))) float f32x4;
typedef __attribute__((ext_vector_type(4))) unsigned short ushort4_;
typedef __attribute__((ext_vector_type(4))) unsigned int uint4v;

// tagged h exchange: u32 = (bf16<<16) | tag ; layout [2 parity][NBG][16 rows][512 cols]
#define HBT_BYTES ((size_t)2 * NBG * 16 * Hdim * 4)  // 524,288
#define HT_OFF ((size_t)524288)
#define XB_OFF ((size_t)786432)
#define XB_BYTES ((size_t)Bsz * Tlen * Din * 2)  // 67,108,864 (x as bf16)

__device__ inline unsigned short f2bf(float f) {
    unsigned int u = __builtin_bit_cast(unsigned int, f);
    unsigned int lsb = (u >> 16) & 1u;
    u += 0x7fffu + lsb;  // RNE
    return (unsigned short)(u >> 16);
}
__device__ inline float sigm_f(float x) { return 1.f / (1.f + __expf(-x)); }
__device__ inline float tanh_f(float x) { return 1.f - 2.f / (__expf(2.f * x) + 1.f); }

__device__ __forceinline__ bool chunk_ok(uint4v v, unsigned want) {
    unsigned m =
        ((v[0] ^ want) | (v[1] ^ want) | (v[2] ^ want) | (v[3] ^ want)) & 0xFFFFu;
    return m == 0;
}
__device__ __forceinline__ void chunk_to_lds(uint4v v, int c, unsigned char* h_lds) {
    int row = c >> 7;
    unsigned lo = (v[0] >> 16) | (v[1] & 0xFFFF0000u);
    unsigned hi = (v[2] >> 16) | (v[3] & 0xFFFF0000u);
    int a = ((row << 10) + ((c & 127) << 3)) ^ ((row & 7) << 4);
    *(unsigned long long*)(h_lds + a) =
        (unsigned long long)lo | ((unsigned long long)hi << 32);
}

// ---- phase 0 (optional): x fp32 -> bf16, natural [B][T][D] layout ----
__global__ __launch_bounds__(256) void xconv(const float* __restrict__ x,
                                             unsigned short* __restrict__ xb) {
    const size_t nthreads = (size_t)2048 * 256;
#pragma unroll
    for (int it = 0; it < 8; ++it) {
        size_t base =
            ((size_t)blockIdx.x * 256 + threadIdx.x + it * nthreads) * 8;
        float4 a = *(const float4*)(x + base);
        float4 b = *(const float4*)(x + base + 4);
        short8 o;
        o[0] = (short)f2bf(a.x); o[1] = (short)f2bf(a.y);
        o[2] = (short)f2bf(a.z); o[3] = (short)f2bf(a.w);
        o[4] = (short)f2bf(b.x); o[5] = (short)f2bf(b.y);
        o[6] = (short)f2bf(b.z); o[7] = (short)f2bf(b.w);
        *(short8*)(xb + base) = o;
    }
}

// ================= persistent recurrence (XB: x pre-converted to bf16) =============
template <bool XB>
__global__ __launch_bounds__(512, 1) void lstm_persist_t(
    const float* __restrict__ x, const unsigned short* __restrict__ xb,
    const float* __restrict__ Wih, const float* __restrict__ Whh,
    const float* __restrict__ bih, const float* __restrict__ bhh,
    unsigned int* __restrict__ hbt, float* __restrict__ hT) {
    __shared__ unsigned char h_lds[16 * 1024];   // [16][512] bf16, swizzled
    __shared__ unsigned char xh_lds[2 * 8192];   // dbuf [16][256] bf16, swizzled
    __shared__ float gates_w[8][16 * 17];        // per-wave [16 batch][16 gcol]

    const int tid = threadIdx.x;
    const int bid = blockIdx.x;
    const int bg = bid & 7;
    const int cg = bid >> 3;
    const int lane = tid & 63;
    const int w = tid >> 6;
    const int n15 = lane & 15;
    const int k8 = lane >> 4;
    const int grow = bg * 16;
    const int gc = n15 & 3;
    const int gsel = n15 >> 2;
    const int myb = k8 * 4 + gsel;
    const int mycol = cg * 32 + w * 4 + gc;
    const int R = (n15 >> 2) * Hdim + mycol;

    // ---- one-time: weight fragments (single bf16) ----
    short8 whh[16], wihh[8];
    {
        const float* wr = Whh + (size_t)R * Hdim;
#pragma unroll
        for (int kc = 0; kc < 16; kc++) {
            const float* p = wr + kc * 32 + k8 * 8;
            short8 f;
#pragma unroll
            for (int e = 0; e < 8; e++) f[e] = (short)f2bf(p[e]);
            whh[kc] = f;
        }
        const float* wr2 = Wih + (size_t)R * Din;
#pragma unroll
        for (int kc = 0; kc < 8; kc++) {
            const float* p = wr2 + kc * 32 + k8 * 8;
            short8 f;
#pragma unroll
            for (int e = 0; e < 8; e++) f[e] = (short)f2bf(p[e]);
            wihh[kc] = f;
        }
    }
    float bias4[4];
#pragma unroll
    for (int g = 0; g < 4; g++) bias4[g] = bih[g * Hdim + mycol] + bhh[g * Hdim + mycol];

    // ---- x staging state ----
    const int xrow = XB ? (tid >> 5) : 0;   // XB: 16B per thread per step
    const int xc8 = XB ? (tid & 31) : 0;
    short8 xr8;       // XB prefetch reg
    float4 xrf[2];    // !XB prefetch regs

    // prologue: stage x[0] -> buf0; prefetch x[1]
    if (XB) {
        const unsigned short* xrowp = xb + ((size_t)(grow + xrow) * Tlen) * Din;
        short8 v = *(const short8*)(xrowp + (size_t)0 * Din + xc8 * 8);
        int a = ((xrow << 9) + (xc8 << 4)) ^ ((xrow & 7) << 4);
        *(short8*)(xh_lds + a) = v;
        xr8 = *(const short8*)(xrowp + (size_t)1 * Din + xc8 * 8);
    } else {
        const float* xbase = x + (size_t)grow * (Tlen * Din);
#pragma unroll
        for (int i = 0; i < 2; i++) {
            int cidx = tid + i * 512;
            int row = cidx >> 6;
            int c4 = cidx & 63;
            float4 v = *(const float4*)(xbase + (size_t)row * (Tlen * Din) + c4 * 4);
            ushort4_ vh;
            vh[0] = f2bf(v.x); vh[1] = f2bf(v.y); vh[2] = f2bf(v.z); vh[3] = f2bf(v.w);
            int a = ((row << 9) + (c4 << 3)) ^ ((row & 7) << 4);
            *(ushort4_*)(xh_lds + a) = vh;
        }
#pragma unroll
        for (int i = 0; i < 2; i++) {
            int cidx = tid + i * 512;
            int row = cidx >> 6;
            int c4 = cidx & 63;
            xrf[i] = *(const float4*)(xbase + (size_t)row * (Tlen * Din) + Din + c4 * 4);
        }
    }
    __syncthreads();

    float c_reg = 0.f, h_last = 0.f;

    for (int t = 0; t < Tlen; ++t) {
        // (1) stage x(t+1) (regs -> LDS buf[(t+1)&1])
        if (t + 1 < Tlen) {
            unsigned char* xdst = xh_lds + ((t + 1) & 1) * 8192;
            if (XB) {
                int a = ((xrow << 9) + (xc8 << 4)) ^ ((xrow & 7) << 4);
                *(short8*)(xdst + a) = xr8;
            } else {
#pragma unroll
                for (int i = 0; i < 2; i++) {
                    int cidx = tid + i * 512;
                    int row = cidx >> 6;
                    int c4 = cidx & 63;
                    ushort4_ vh;
                    vh[0] = f2bf(xrf[i].x); vh[1] = f2bf(xrf[i].y);
                    vh[2] = f2bf(xrf[i].z); vh[3] = f2bf(xrf[i].w);
                    int a = ((row << 9) + (c4 << 3)) ^ ((row & 7) << 4);
                    *(ushort4_*)(xdst + a) = vh;
                }
            }
        }

        // (2) x-side MFMAs on buf[t&1] (8 single-bf16)
        unsigned char* xh = xh_lds + (t & 1) * 8192;
        f32x4 acc0 = {0.f, 0.f, 0.f, 0.f}, acc1 = {0.f, 0.f, 0.f, 0.f};
#pragma unroll
        for (int kc = 0; kc < 8; kc++) {
            int a = (((n15 << 9) + (kc << 6) + (k8 << 4)) ^ ((n15 & 7) << 4));
            short8 xv = *(const short8*)(xh + a);
            if (kc & 1)
                acc1 = __builtin_amdgcn_mfma_f32_16x16x32_bf16(xv, wihh[kc], acc1, 0, 0, 0);
            else
                acc0 = __builtin_amdgcn_mfma_f32_16x16x32_bf16(xv, wihh[kc], acc0, 0, 0, 0);
        }

        // (3) issue-LATE sweep + validate (first L3 access lands after peer publishes)
        if (t > 0) {
            const unsigned int* hb = hbt + ((size_t)(t & 1) * NBG + bg) * 8192;
            const unsigned int* p0 = hb + (size_t)tid * 4;
            const unsigned int* p1 = hb + (size_t)(tid + 512) * 4;
            const unsigned int* p2 = hb + (size_t)(tid + 1024) * 4;
            const unsigned int* p3 = hb + (size_t)(tid + 1536) * 4;
            uint4v r0, r1, r2, r3;
            asm volatile(
                "global_load_dwordx4 %0, %4, off sc0 sc1\n\t"
                "global_load_dwordx4 %1, %5, off sc0 sc1\n\t"
                "global_load_dwordx4 %2, %6, off sc0 sc1\n\t"
                "global_load_dwordx4 %3, %7, off sc0 sc1"
                : "=&v"(r0), "=&v"(r1), "=&v"(r2), "=&v"(r3)
                : "v"(p0), "v"(p1), "v"(p2), "v"(p3)
                : "memory");
            const unsigned want = (unsigned)t;
            asm volatile("s_waitcnt vmcnt(0)" ::: "memory");
            __builtin_amdgcn_sched_barrier(0);
            unsigned need = 0;
            if (chunk_ok(r0, want)) chunk_to_lds(r0, tid, h_lds); else need |= 1u;
            if (chunk_ok(r1, want)) chunk_to_lds(r1, tid + 512, h_lds); else need |= 2u;
            if (chunk_ok(r2, want)) chunk_to_lds(r2, tid + 1024, h_lds); else need |= 4u;
            if (chunk_ok(r3, want)) chunk_to_lds(r3, tid + 1536, h_lds); else need |= 8u;
            int rounds = 0;
            while (need && ++rounds < (1 << 14)) {
                if (rounds > 6) __builtin_amdgcn_s_sleep(1);
                if (need & 1u)
                    asm volatile("global_load_dwordx4 %0, %1, off sc0 sc1"
                                 : "=&v"(r0) : "v"(p0) : "memory");
                if (need & 2u)
                    asm volatile("global_load_dwordx4 %0, %1, off sc0 sc1"
                                 : "=&v"(r1) : "v"(p1) : "memory");
                if (need & 4u)
                    asm volatile("global_load_dwordx4 %0, %1, off sc0 sc1"
                                 : "=&v"(r2) : "v"(p2) : "memory");
                if (need & 8u)
                    asm volatile("global_load_dwordx4 %0, %1, off sc0 sc1"
                                 : "=&v"(r3) : "v"(p3) : "memory");
                asm volatile("s_waitcnt vmcnt(0)" ::: "memory");
                __builtin_amdgcn_sched_barrier(0);
                if ((need & 1u) && chunk_ok(r0, want)) { chunk_to_lds(r0, tid, h_lds); need &= ~1u; }
                if ((need & 2u) && chunk_ok(r1, want)) { chunk_to_lds(r1, tid + 512, h_lds); need &= ~2u; }
                if ((need & 4u) && chunk_ok(r2, want)) { chunk_to_lds(r2, tid + 1024, h_lds); need &= ~4u; }
                if ((need & 8u) && chunk_ok(r3, want)) { chunk_to_lds(r3, tid + 1536, h_lds); need &= ~8u; }
            }
        } else {
#pragma unroll
            for (int i = 0; i < 4; i++) {
                int c = tid + i * 512;
                int row = c >> 7;
                int a = ((row << 10) + ((c & 127) << 3)) ^ ((row & 7) << 4);
                *(unsigned long long*)(h_lds + a) = 0ULL;
            }
        }
        // barrier A: h_lds + x stage ready (LDS hazards only)
        asm volatile("s_waitcnt lgkmcnt(0)" ::: "memory");
        __builtin_amdgcn_s_barrier();
        __builtin_amdgcn_sched_barrier(0);

        // (4) h-side MFMAs
#pragma unroll
        for (int kc = 0; kc < 16; kc++) {
            short8 a = *(const short8*)(h_lds + (((n15 << 10) + (kc << 6) + (k8 << 4)) ^
                                                ((n15 & 7) << 4)));
            if (kc & 1)
                acc1 = __builtin_amdgcn_mfma_f32_16x16x32_bf16(a, whh[kc], acc1, 0, 0, 0);
            else
                acc0 = __builtin_amdgcn_mfma_f32_16x16x32_bf16(a, whh[kc], acc0, 0, 0, 0);
        }

        // (5) prefetch x(t+2) -> regs (in flight across barrier C)
        if (t + 2 < Tlen) {
            if (XB) {
                xr8 = *(const short8*)(xb + ((size_t)(grow + xrow) * Tlen + (t + 2)) * Din +
                                       xc8 * 8);
            } else {
                const float* xbase =
                    x + (size_t)grow * (Tlen * Din) + (size_t)(t + 2) * Din;
#pragma unroll
                for (int i = 0; i < 2; i++) {
                    int cidx = tid + i * 512;
                    int row = cidx >> 6;
                    int c4 = cidx & 63;
                    xrf[i] = *(const float4*)(xbase + (size_t)row * (Tlen * Din) + c4 * 4);
                }
            }
        }

        // (6) gates -> wave-private LDS; cell; fire-and-forget tagged publish
        float* gt = gates_w[w];
#pragma unroll
        for (int j2 = 0; j2 < 4; j2++) gt[(k8 * 4 + j2) * 17 + n15] = acc0[j2] + acc1[j2];
        {
            float pre[4];
#pragma unroll
            for (int g = 0; g < 4; g++) pre[g] = gt[myb * 17 + g * 4 + gc] + bias4[g];
            float ig = sigm_f(pre[0]);
            float fg = sigm_f(pre[1]);
            float gg = tanh_f(pre[2]);
            float og = sigm_f(pre[3]);
            c_reg = fg * c_reg + ig * gg;
            h_last = og * tanh_f(c_reg);
            unsigned int word = ((unsigned int)f2bf(h_last) << 16) | (unsigned)(t + 1);
            unsigned int* dst = hbt + ((size_t)((t + 1) & 1) * NBG + bg) * 8192 +
                                (size_t)myb * Hdim + mycol;
            __hip_atomic_store(dst, word, __ATOMIC_RELAXED, __HIP_MEMORY_SCOPE_AGENT);
        }
        // barrier C: LDS WAR separation only (publish + x prefetch stay in flight)
        asm volatile("s_waitcnt lgkmcnt(0)" ::: "memory");
        __builtin_amdgcn_s_barrier();
        __builtin_amdgcn_sched_barrier(0);
    }
    hT[(size_t)(grow + myb) * Hdim + mycol] = h_last;
}

__global__ __launch_bounds__(256) void out_proj(const float* __restrict__ hT,
                                                const float* __restrict__ Wout,
                                                const float* __restrict__ bout,
                                                float* __restrict__ out) {
    __shared__ float h_s[16 * 512];
    __shared__ float w_s[64 * 69];
    const int tid = threadIdx.x;
    const int bt = blockIdx.x >> 2;
    const int ot = blockIdx.x & 3;
#pragma unroll
    for (int i = 0; i < 8; i++) {
        int cidx = tid + i * 256;
        int row = cidx >> 7;
        int c4 = cidx & 127;
        *(float4*)(&h_s[row * 512 + c4 * 4]) =
            *(const float4*)(hT + (size_t)(bt * 16 + row) * 512 + c4 * 4);
    }
    const int o = tid & 63;
    const int bq = tid >> 6;
    float acc[4] = {0.f, 0.f, 0.f, 0.f};
    for (int kc = 0; kc < 8; kc++) {
        __syncthreads();
#pragma unroll
        for (int i = 0; i < 4; i++) {
            int cidx = tid + i * 256;
            int row = cidx >> 4;
            int c4 = cidx & 15;
            float4 v = *(const float4*)(Wout + (size_t)(ot * 64 + row) * 512 + kc * 64 +
                                        c4 * 4);
            float* dst = &w_s[row * 69 + c4 * 4];
            dst[0] = v.x;
            dst[1] = v.y;
            dst[2] = v.z;
            dst[3] = v.w;
        }
        __syncthreads();
#pragma unroll 16
        for (int k = 0; k < 64; k++) {
            float wv = w_s[o * 69 + k];
#pragma unroll
            for (int bi = 0; bi < 4; bi++)
                acc[bi] += h_s[(bq * 4 + bi) * 512 + kc * 64 + k] * wv;
        }
    }
    float bo = bout[ot * 64 + o];
#pragma unroll
    for (int bi = 0; bi < 4; bi++)
        out[(size_t)(bt * 16 + bq * 4 + bi) * 256 + ot * 64 + o] = acc[bi] + bo;
}

extern "C" void kernel_launch(void* const* d_in, const int* in_sizes, int n_in,
                              void* d_out, int out_size, void* d_ws, size_t ws_size,
                              hipStream_t stream) {
    const float* x = (const float*)d_in[0];
    const float* Wih = (const float*)d_in[1];
    const float* Whh = (const float*)d_in[2];
    const float* bih = (const float*)d_in[3];
    const float* bhh = (const float*)d_in[4];
    const float* Wout = (const float*)d_in[5];
    const float* bout = (const float*)d_in[6];
    float* out = (float*)d_out;

    char* ws = (char*)d_ws;
    unsigned int* hbt = (unsigned int*)ws;
    float* hT = (float*)(ws + HT_OFF);
    unsigned short* xbuf = (unsigned short*)(ws + XB_OFF);

    hipMemsetAsync(hbt, 0, HBT_BYTES, stream);  // clear tags: replay determinism
    if (ws_size >= XB_OFF + XB_BYTES) {
        xconv<<<dim3(2048), dim3(256), 0, stream>>>(x, xbuf);
        lstm_persist_t<true><<<dim3(NBG * NCG), dim3(512), 0, stream>>>(
            x, xbuf, Wih, Whh, bih, bhh, hbt, hT);
    } else {
        lstm_persist_t<false><<<dim3(NBG * NCG), dim3(512), 0, stream>>>(
            x, (const unsigned short*)nullptr, Wih, Whh, bih, bhh, hbt, hT);
    }
    out_proj<<<dim3(32), dim3(256), 0, stream>>>(hT, Wout, bout, out);
}